// Round 1
// baseline (1447.895 us; speedup 1.0000x reference)
//
#include <hip/hip_runtime.h>
#include <stdint.h>

#define T_TOK 8192
#define HDIM  2048
#define NEXP  8
#define TILE  128

typedef __bf16 bf16x8 __attribute__((ext_vector_type(8)));
typedef float  f32x4  __attribute__((ext_vector_type(4)));
typedef unsigned short u16;
typedef u16    u16x8  __attribute__((ext_vector_type(8)));

static __device__ __forceinline__ u16 f2bf(float f) {
    union { float f; unsigned u; } v; v.f = f;
    unsigned u = v.u;
    u = (u + 0x7FFFu + ((u >> 16) & 1u)) >> 16;   // RNE
    return (u16)u;
}

// fp32 -> bf16, 8 elems/thread
__global__ __launch_bounds__(256) void cvt_kernel(const float* __restrict__ in,
                                                  u16* __restrict__ out, int n8) {
    int i = blockIdx.x * 256 + threadIdx.x;
    if (i >= n8) return;
    const float4* p = (const float4*)in + (size_t)i * 2;
    float4 a = p[0], b = p[1];
    u16x8 r;
    r[0] = f2bf(a.x); r[1] = f2bf(a.y); r[2] = f2bf(a.z); r[3] = f2bf(a.w);
    r[4] = f2bf(b.x); r[5] = f2bf(b.y); r[6] = f2bf(b.z); r[7] = f2bf(b.w);
    ((u16x8*)out)[i] = r;
}

// one wave per token: logits, top-2, scatter to per-expert lists
__global__ __launch_bounds__(256) void router_kernel(const float* __restrict__ x,
                                                     const float* __restrict__ gw,
                                                     float* __restrict__ logits_out,
                                                     int* __restrict__ cnt,
                                                     int* __restrict__ rows,
                                                     float* __restrict__ wts) {
    int wave = threadIdx.x >> 6;
    int lane = threadIdx.x & 63;
    int t = blockIdx.x * 4 + wave;
    const float4* x4 = (const float4*)(x + (size_t)t * HDIM);
    const float4* g4 = (const float4*)gw;
    float acc[NEXP] = {};
    #pragma unroll
    for (int i = 0; i < HDIM / 4 / 64; i++) {     // 8 iters
        int idx = lane + i * 64;
        float4 xv = x4[idx];
        #pragma unroll
        for (int e = 0; e < NEXP; e++) {
            float4 gv = g4[e * (HDIM / 4) + idx];
            acc[e] += xv.x * gv.x + xv.y * gv.y + xv.z * gv.z + xv.w * gv.w;
        }
    }
    #pragma unroll
    for (int e = 0; e < NEXP; e++) {
        #pragma unroll
        for (int off = 32; off > 0; off >>= 1)
            acc[e] += __shfl_xor(acc[e], off, 64);
    }
    if (lane == 0) {
        #pragma unroll
        for (int e = 0; e < NEXP; e++) logits_out[(size_t)t * NEXP + e] = acc[e];
        int e0 = 0;
        #pragma unroll
        for (int e = 1; e < NEXP; e++) if (acc[e] > acc[e0]) e0 = e;
        int e1 = (e0 == 0) ? 1 : 0;
        #pragma unroll
        for (int e = 0; e < NEXP; e++) if (e != e0 && acc[e] > acc[e1]) e1 = e;
        // renormalized top-2 softmax: w0 = p0/(p0+p1) = sigmoid(l0-l1)
        float w0 = 1.0f / (1.0f + expf(acc[e1] - acc[e0]));
        float w1 = 1.0f - w0;
        int p0 = atomicAdd(&cnt[e0], 1);
        rows[e0 * T_TOK + p0] = t; wts[e0 * T_TOK + p0] = w0;
        int p1 = atomicAdd(&cnt[e1], 1);
        rows[e1 * T_TOK + p1] = t; wts[e1 * T_TOK + p1] = w1;
    }
}

// grouped GEMM: Y = gather(Xbf) @ We^T, scaled + atomic-scattered into out.
// grid.x = expert*64 + row_tile, grid.y = col_tile (HDIM/128)
__global__ __launch_bounds__(256) void moe_gemm(const u16* __restrict__ xb,
                                                const u16* __restrict__ wb,
                                                const int* __restrict__ cnt,
                                                const int* __restrict__ rows,
                                                const float* __restrict__ wts,
                                                float* __restrict__ out) {
    int e  = blockIdx.x >> 6;
    int rt = blockIdx.x & 63;
    int count = cnt[e];
    int rowBase = rt * TILE;
    if (rowBase >= count) return;
    int nb = blockIdx.y * TILE;

    const u16*   W     = wb  + (size_t)e * HDIM * HDIM;
    const int*   rlist = rows + e * T_TOK;
    const float* wlist = wts  + e * T_TOK;

    int lane = threadIdx.x & 63;
    int wave = threadIdx.x >> 6;
    int wr = wave >> 1, wc = wave & 1;
    int mbase  = rowBase + wr * 64;
    int nbase  = nb + wc * 64;
    int lrow   = lane & 15;         // m (A) / n (B) / col (D) within 16-tile
    int kq     = (lane >> 4) * 8;   // k offset of this quad within 32

    // A row pointers (clamped gather)
    const u16* aptr[4];
    #pragma unroll
    for (int mt = 0; mt < 4; mt++) {
        int r = mbase + mt * 16 + lrow;
        int tok = rlist[min(r, count - 1)];
        aptr[mt] = xb + (size_t)tok * HDIM + kq;
    }
    const u16* bptr[4];
    #pragma unroll
    for (int nt = 0; nt < 4; nt++) {
        int n = nbase + nt * 16 + lrow;
        bptr[nt] = W + (size_t)n * HDIM + kq;
    }

    f32x4 acc[4][4] = {};
    #pragma unroll 4
    for (int kb = 0; kb < HDIM; kb += 32) {
        bf16x8 a[4], b[4];
        #pragma unroll
        for (int mt = 0; mt < 4; mt++) a[mt] = *(const bf16x8*)(aptr[mt] + kb);
        #pragma unroll
        for (int nt = 0; nt < 4; nt++) b[nt] = *(const bf16x8*)(bptr[nt] + kb);
        #pragma unroll
        for (int mt = 0; mt < 4; mt++)
            #pragma unroll
            for (int nt = 0; nt < 4; nt++)
                acc[mt][nt] = __builtin_amdgcn_mfma_f32_16x16x32_bf16(
                                  a[mt], b[nt], acc[mt][nt], 0, 0, 0);
    }

    // epilogue: D[row=(lane>>4)*4+r][col=lane&15] per 16x16 tile
    int srow = (lane >> 4) * 4;
    #pragma unroll
    for (int mt = 0; mt < 4; mt++) {
        #pragma unroll
        for (int r = 0; r < 4; r++) {
            int row = mbase + mt * 16 + srow + r;
            if (row < count) {
                int   tok = rlist[row];
                float wgt = wlist[row];
                #pragma unroll
                for (int nt = 0; nt < 4; nt++) {
                    int col = nbase + nt * 16 + lrow;
                    atomicAdd(out + (size_t)tok * HDIM + col, wgt * acc[mt][nt][r]);
                }
            }
        }
    }
}

extern "C" void kernel_launch(void* const* d_in, const int* in_sizes, int n_in,
                              void* d_out, int out_size, void* d_ws, size_t ws_size,
                              hipStream_t stream) {
    const float* x  = (const float*)d_in[0];   // [T, H]
    const float* gw = (const float*)d_in[1];   // [E, H]
    const float* ew = (const float*)d_in[2];   // [E, H, H]
    float* out    = (float*)d_out;             // [T, H] fp32
    float* logits = out + (size_t)T_TOK * HDIM;

    char* ws = (char*)d_ws;
    int*   cnt  = (int*)ws;                                   // 32 B
    int*   rows = (int*)(ws + 1024);                          // 256 KB
    float* wts  = (float*)(ws + 1024 + 262144);               // 256 KB
    u16*   xb   = (u16*)(ws + 1024 + 2 * 262144);             // 32 MB
    u16*   wb   = xb + (size_t)T_TOK * HDIM;                  // 64 MB

    hipMemsetAsync(d_out, 0, (size_t)T_TOK * HDIM * sizeof(float), stream);
    hipMemsetAsync(cnt, 0, NEXP * sizeof(int), stream);

    int nx8 = T_TOK * HDIM / 8;
    cvt_kernel<<<(nx8 + 255) / 256, 256, 0, stream>>>(x, xb, nx8);
    int nw8 = NEXP * HDIM * HDIM / 8;
    cvt_kernel<<<(nw8 + 255) / 256, 256, 0, stream>>>(ew, wb, nw8);

    router_kernel<<<T_TOK / 4, 256, 0, stream>>>(x, gw, logits, cnt, rows, wts);

    dim3 grid(NEXP * (T_TOK / TILE), HDIM / TILE);
    moe_gemm<<<grid, 256, 0, stream>>>(xb, wb, cnt, rows, wts, out);
}

// Round 2
// 865.373 us; speedup vs baseline: 1.6731x; 1.6731x over previous
//
#include <hip/hip_runtime.h>
#include <stdint.h>

#define T_TOK 8192
#define HDIM  2048
#define NEXP  8
#define TILE  128
#define BK    64            // k-elems per LDS tile; 8 chunks of 8 bf16 per row

typedef __bf16 bf16x8 __attribute__((ext_vector_type(8)));
typedef float  f32x4  __attribute__((ext_vector_type(4)));
typedef unsigned short u16;
typedef u16    u16x8  __attribute__((ext_vector_type(8)));

typedef const __attribute__((address_space(1))) void* gptr_t;
typedef __attribute__((address_space(3))) void* lptr_t;

static __device__ __forceinline__ u16 f2bf(float f) {
    union { float f; unsigned u; } v; v.f = f;
    unsigned u = v.u;
    u = (u + 0x7FFFu + ((u >> 16) & 1u)) >> 16;   // RNE
    return (u16)u;
}

// fp32 -> bf16, 8 elems/thread
__global__ __launch_bounds__(256) void cvt_kernel(const float* __restrict__ in,
                                                  u16* __restrict__ out, int n8) {
    int i = blockIdx.x * 256 + threadIdx.x;
    if (i >= n8) return;
    const float4* p = (const float4*)in + (size_t)i * 2;
    float4 a = p[0], b = p[1];
    u16x8 r;
    r[0] = f2bf(a.x); r[1] = f2bf(a.y); r[2] = f2bf(a.z); r[3] = f2bf(a.w);
    r[4] = f2bf(b.x); r[5] = f2bf(b.y); r[6] = f2bf(b.z); r[7] = f2bf(b.w);
    ((u16x8*)out)[i] = r;
}

// one wave per token: logits, top-2, scatter to per-expert lists
__global__ __launch_bounds__(256) void router_kernel(const float* __restrict__ x,
                                                     const float* __restrict__ gw,
                                                     float* __restrict__ logits_out,
                                                     int* __restrict__ cnt,
                                                     int* __restrict__ rows,
                                                     float* __restrict__ wts) {
    int wave = threadIdx.x >> 6;
    int lane = threadIdx.x & 63;
    int t = blockIdx.x * 4 + wave;
    const float4* x4 = (const float4*)(x + (size_t)t * HDIM);
    const float4* g4 = (const float4*)gw;
    float acc[NEXP] = {};
    #pragma unroll
    for (int i = 0; i < HDIM / 4 / 64; i++) {     // 8 iters
        int idx = lane + i * 64;
        float4 xv = x4[idx];
        #pragma unroll
        for (int e = 0; e < NEXP; e++) {
            float4 gv = g4[e * (HDIM / 4) + idx];
            acc[e] += xv.x * gv.x + xv.y * gv.y + xv.z * gv.z + xv.w * gv.w;
        }
    }
    #pragma unroll
    for (int e = 0; e < NEXP; e++) {
        #pragma unroll
        for (int off = 32; off > 0; off >>= 1)
            acc[e] += __shfl_xor(acc[e], off, 64);
    }
    if (lane == 0) {
        #pragma unroll
        for (int e = 0; e < NEXP; e++) logits_out[(size_t)t * NEXP + e] = acc[e];
        int e0 = 0;
        #pragma unroll
        for (int e = 1; e < NEXP; e++) if (acc[e] > acc[e0]) e0 = e;
        int e1 = (e0 == 0) ? 1 : 0;
        #pragma unroll
        for (int e = 0; e < NEXP; e++) if (e != e0 && acc[e] > acc[e1]) e1 = e;
        float w0 = 1.0f / (1.0f + expf(acc[e1] - acc[e0]));
        float w1 = 1.0f - w0;
        int p0 = atomicAdd(&cnt[e0], 1);
        rows[e0 * T_TOK + p0] = t; wts[e0 * T_TOK + p0] = w0;
        int p1 = atomicAdd(&cnt[e1], 1);
        rows[e1 * T_TOK + p1] = t; wts[e1 * T_TOK + p1] = w1;
    }
}

// grouped GEMM, m97 structure: 128x128 tile, BK=64, global_load_lds staging,
// XOR-swizzled chunk layout (source-side swizzle keeps LDS dest contiguous).
// LDS slot for logical (row, chunk): slot = row*8 + (chunk ^ (row&7)), 16B/slot.
__global__ __launch_bounds__(256) void moe_gemm(const u16* __restrict__ xb,
                                                const u16* __restrict__ wb,
                                                const int* __restrict__ cnt,
                                                const int* __restrict__ rows,
                                                const float* __restrict__ wts,
                                                float* __restrict__ out) {
    int e  = blockIdx.x >> 6;
    int rt = blockIdx.x & 63;
    int count = cnt[e];
    int rowBase = rt * TILE;
    if (rowBase >= count) return;
    int nb = blockIdx.y * TILE;

    const u16*   W     = wb  + (size_t)e * HDIM * HDIM;
    const int*   rlist = rows + e * T_TOK;
    const float* wlist = wts  + e * T_TOK;

    __shared__ u16 As[TILE * BK];   // 16 KB
    __shared__ u16 Bs[TILE * BK];   // 16 KB

    int tid  = threadIdx.x;
    int lane = tid & 63;
    int wave = tid >> 6;
    int wr = wave >> 1, wc = wave & 1;

    // ---- staging setup: thread tid stages slot (p*256 + tid), p = 0..3 ----
    // row = slot>>3, stored chunk = slot&7, logical chunk = (slot&7)^(row&7)
    const u16* a_src[4];
    const u16* b_src[4];
    #pragma unroll
    for (int p = 0; p < 4; p++) {
        int row  = (tid >> 3) + p * 32;            // 0..127
        int clog = (tid & 7) ^ (row & 7);
        int tok  = rlist[min(rowBase + row, count - 1)];
        a_src[p] = xb + (size_t)tok * HDIM + clog * 8;
        b_src[p] = W + (size_t)(nb + row) * HDIM + clog * 8;
    }
    // wave-uniform LDS dest bases (lane writes base + lane*16)
    int wslot = (tid & ~63);                        // wave-uniform
    u16* lds_a[4]; u16* lds_b[4];
    #pragma unroll
    for (int p = 0; p < 4; p++) {
        lds_a[p] = As + (size_t)(p * 256 + wslot) * 8;
        lds_b[p] = Bs + (size_t)(p * 256 + wslot) * 8;
    }

    // ---- fragment read addressing ----
    int lrow = lane & 15;
    int kq   = lane >> 4;                           // quad id: chunk sub-index
    int mloc[4], nloc[4];
    #pragma unroll
    for (int i = 0; i < 4; i++) {
        mloc[i] = wr * 64 + i * 16 + lrow;          // local A row
        nloc[i] = wc * 64 + i * 16 + lrow;          // local B row
    }

    f32x4 acc[4][4] = {};

    for (int kb = 0; kb < HDIM; kb += BK) {
        __syncthreads();                            // LDS free to overwrite
        #pragma unroll
        for (int p = 0; p < 4; p++) {
            __builtin_amdgcn_global_load_lds((gptr_t)(a_src[p] + kb),
                                             (lptr_t)lds_a[p], 16, 0, 0);
            __builtin_amdgcn_global_load_lds((gptr_t)(b_src[p] + kb),
                                             (lptr_t)lds_b[p], 16, 0, 0);
        }
        __syncthreads();                            // drains vmcnt → data visible

        #pragma unroll
        for (int s = 0; s < 2; s++) {               // two 32-k steps
            int chunk = s * 4 + kq;
            bf16x8 a[4], b[4];
            #pragma unroll
            for (int i = 0; i < 4; i++) {
                int aslot = (mloc[i] << 3) | (chunk ^ (mloc[i] & 7));
                int bslot = (nloc[i] << 3) | (chunk ^ (nloc[i] & 7));
                a[i] = *(const bf16x8*)(As + aslot * 8);
                b[i] = *(const bf16x8*)(Bs + bslot * 8);
            }
            #pragma unroll
            for (int mt = 0; mt < 4; mt++)
                #pragma unroll
                for (int nt = 0; nt < 4; nt++)
                    acc[mt][nt] = __builtin_amdgcn_mfma_f32_16x16x32_bf16(
                                      a[mt], b[nt], acc[mt][nt], 0, 0, 0);
        }
    }

    // epilogue: D[row=(lane>>4)*4+r][col=lane&15] per 16x16 tile
    int srow = (lane >> 4) * 4;
    #pragma unroll
    for (int mt = 0; mt < 4; mt++) {
        #pragma unroll
        for (int r = 0; r < 4; r++) {
            int row = rowBase + wr * 64 + mt * 16 + srow + r;
            if (row < count) {
                int   tok = rlist[row];
                float wgt = wlist[row];
                #pragma unroll
                for (int nt = 0; nt < 4; nt++) {
                    int col = nb + wc * 64 + nt * 16 + lrow;
                    atomicAdd(out + (size_t)tok * HDIM + col, wgt * acc[mt][nt][r]);
                }
            }
        }
    }
}

extern "C" void kernel_launch(void* const* d_in, const int* in_sizes, int n_in,
                              void* d_out, int out_size, void* d_ws, size_t ws_size,
                              hipStream_t stream) {
    const float* x  = (const float*)d_in[0];   // [T, H]
    const float* gw = (const float*)d_in[1];   // [E, H]
    const float* ew = (const float*)d_in[2];   // [E, H, H]
    float* out    = (float*)d_out;             // [T, H] fp32
    float* logits = out + (size_t)T_TOK * HDIM;

    char* ws = (char*)d_ws;
    int*   cnt  = (int*)ws;                                   // 32 B
    int*   rows = (int*)(ws + 1024);                          // 256 KB
    float* wts  = (float*)(ws + 1024 + 262144);               // 256 KB
    u16*   xb   = (u16*)(ws + 1024 + 2 * 262144);             // 32 MB
    u16*   wb   = xb + (size_t)T_TOK * HDIM;                  // 64 MB

    hipMemsetAsync(d_out, 0, (size_t)T_TOK * HDIM * sizeof(float), stream);
    hipMemsetAsync(cnt, 0, NEXP * sizeof(int), stream);

    int nx8 = T_TOK * HDIM / 8;
    cvt_kernel<<<(nx8 + 255) / 256, 256, 0, stream>>>(x, xb, nx8);
    int nw8 = NEXP * HDIM * HDIM / 8;
    cvt_kernel<<<(nw8 + 255) / 256, 256, 0, stream>>>(ew, wb, nw8);

    router_kernel<<<T_TOK / 4, 256, 0, stream>>>(x, gw, logits, cnt, rows, wts);

    dim3 grid(NEXP * (T_TOK / TILE), HDIM / TILE);
    moe_gemm<<<grid, 256, 0, stream>>>(xb, wb, cnt, rows, wts, out);
}

// Round 3
// 644.109 us; speedup vs baseline: 2.2479x; 1.3435x over previous
//
#include <hip/hip_runtime.h>
#include <stdint.h>

#define T_TOK 8192
#define HDIM  2048
#define NEXP  8
#define TILE  128
#define BK    64            // k-elems per LDS tile; 8 chunks of 8 bf16 per row
#define RTOK  32            // tokens per router block

typedef __bf16 bf16x8 __attribute__((ext_vector_type(8)));
typedef float  f32x4  __attribute__((ext_vector_type(4)));
typedef unsigned short u16;
typedef u16    u16x8  __attribute__((ext_vector_type(8)));

typedef const __attribute__((address_space(1))) void* gptr_t;
typedef __attribute__((address_space(3))) void* lptr_t;

static __device__ __forceinline__ u16 f2bf(float f) {
    union { float f; unsigned u; } v; v.f = f;
    unsigned u = v.u;
    u = (u + 0x7FFFu + ((u >> 16) & 1u)) >> 16;   // RNE
    return (u16)u;
}

// fp32 -> bf16, 8 elems/thread (weights only; x is converted in router)
__global__ __launch_bounds__(256) void cvt_kernel(const float* __restrict__ in,
                                                  u16* __restrict__ out, int n8) {
    int i = blockIdx.x * 256 + threadIdx.x;
    if (i >= n8) return;
    const float4* p = (const float4*)in + (size_t)i * 2;
    float4 a = p[0], b = p[1];
    u16x8 r;
    r[0] = f2bf(a.x); r[1] = f2bf(a.y); r[2] = f2bf(a.z); r[3] = f2bf(a.w);
    r[4] = f2bf(b.x); r[5] = f2bf(b.y); r[6] = f2bf(b.z); r[7] = f2bf(b.w);
    ((u16x8*)out)[i] = r;
}

// Router: 32 tokens/block (4 waves x 8 tokens). Computes logits, top-2,
// converts x->bf16 on the fly, and scatters via per-block LDS lists +
// 8 global atomics per block (vs 2/token before — kills same-address
// atomic serialization).
__global__ __launch_bounds__(256) void router_kernel(const float* __restrict__ x,
                                                     const float* __restrict__ gw,
                                                     u16* __restrict__ xb,
                                                     float* __restrict__ logits_out,
                                                     int* __restrict__ cnt,
                                                     int* __restrict__ rows,
                                                     float* __restrict__ wts) {
    __shared__ int   lcnt[NEXP];
    __shared__ int   lbase[NEXP];
    __shared__ int   lrows[NEXP][RTOK];
    __shared__ float lwtsS[NEXP][RTOK];

    int tid  = threadIdx.x;
    int lane = tid & 63;
    int wave = tid >> 6;
    if (tid < NEXP) lcnt[tid] = 0;
    __syncthreads();

    int t0 = blockIdx.x * RTOK + wave * 8;
    const float4* g4 = (const float4*)gw;

    float acc[8][NEXP] = {};
    #pragma unroll
    for (int i = 0; i < HDIM / 4 / 64; i++) {      // 8 iters
        int idx = lane + i * 64;
        float4 gv[NEXP];
        #pragma unroll
        for (int e = 0; e < NEXP; e++) gv[e] = g4[e * (HDIM / 4) + idx];
        #pragma unroll
        for (int tk = 0; tk < 8; tk++) {
            int t = t0 + tk;
            float4 xv = ((const float4*)(x + (size_t)t * HDIM))[idx];
            ushort4 h;
            h.x = f2bf(xv.x); h.y = f2bf(xv.y); h.z = f2bf(xv.z); h.w = f2bf(xv.w);
            ((ushort4*)(xb + (size_t)t * HDIM))[idx] = h;
            #pragma unroll
            for (int e = 0; e < NEXP; e++)
                acc[tk][e] += xv.x * gv[e].x + xv.y * gv[e].y +
                              xv.z * gv[e].z + xv.w * gv[e].w;
        }
    }
    #pragma unroll
    for (int tk = 0; tk < 8; tk++)
        #pragma unroll
        for (int e = 0; e < NEXP; e++)
            #pragma unroll
            for (int off = 32; off > 0; off >>= 1)
                acc[tk][e] += __shfl_xor(acc[tk][e], off, 64);

    if (lane == 0) {
        #pragma unroll
        for (int tk = 0; tk < 8; tk++) {
            int t = t0 + tk;
            #pragma unroll
            for (int e = 0; e < NEXP; e++) logits_out[(size_t)t * NEXP + e] = acc[tk][e];
            int e0 = 0;
            #pragma unroll
            for (int e = 1; e < NEXP; e++) if (acc[tk][e] > acc[tk][e0]) e0 = e;
            int e1 = (e0 == 0) ? 1 : 0;
            #pragma unroll
            for (int e = 0; e < NEXP; e++)
                if (e != e0 && acc[tk][e] > acc[tk][e1]) e1 = e;
            float w0 = 1.0f / (1.0f + expf(acc[tk][e1] - acc[tk][e0]));
            int p0 = atomicAdd(&lcnt[e0], 1);
            lrows[e0][p0] = t; lwtsS[e0][p0] = w0;
            int p1 = atomicAdd(&lcnt[e1], 1);
            lrows[e1][p1] = t; lwtsS[e1][p1] = 1.0f - w0;
        }
    }
    __syncthreads();
    if (tid < NEXP) lbase[tid] = atomicAdd(&cnt[tid], lcnt[tid]);
    __syncthreads();
    int e = tid >> 5, j = tid & 31;                 // 8 experts x 32 slots
    if (j < lcnt[e]) {
        int b = lbase[e] + j;
        rows[e * T_TOK + b] = lrows[e][j];
        wts[e * T_TOK + b]  = lwtsS[e][j];
    }
}

// grouped GEMM, m97 structure + XCD-aware swizzle:
// linear id p -> (g, rt) with all row-tiles of group g on XCD g%8, so the
// shared B K-slabs stay in one XCD's L2.
__global__ __launch_bounds__(256) void moe_gemm(const u16* __restrict__ xb,
                                                const u16* __restrict__ wb,
                                                const int* __restrict__ cnt,
                                                const int* __restrict__ rows,
                                                const float* __restrict__ wts,
                                                float* __restrict__ out) {
    int p  = blockIdx.x;
    int xc = p & 7;
    int q  = p >> 3;
    int rt = q & 63;
    int g  = (q >> 6) * 8 + xc;      // 0..127 = expert*16 + coltile
    int e  = g >> 4;
    int nb = (g & 15) * TILE;

    int count = cnt[e];
    int rowBase = rt * TILE;
    if (rowBase >= count) return;

    const u16*   W     = wb  + (size_t)e * HDIM * HDIM;
    const int*   rlist = rows + e * T_TOK;
    const float* wlist = wts  + e * T_TOK;

    __shared__ u16 As[TILE * BK];   // 16 KB
    __shared__ u16 Bs[TILE * BK];   // 16 KB

    int tid  = threadIdx.x;
    int lane = tid & 63;
    int wave = tid >> 6;
    int wr = wave >> 1, wc = wave & 1;

    // staging: thread tid stages slot (p*256 + tid); row = slot>>3,
    // stored chunk = slot&7, logical chunk = (slot&7)^(row&7)
    const u16* a_src[4];
    const u16* b_src[4];
    #pragma unroll
    for (int pp = 0; pp < 4; pp++) {
        int row  = (tid >> 3) + pp * 32;            // 0..127
        int clog = (tid & 7) ^ (row & 7);
        int tok  = rlist[min(rowBase + row, count - 1)];
        a_src[pp] = xb + (size_t)tok * HDIM + clog * 8;
        b_src[pp] = W + (size_t)(nb + row) * HDIM + clog * 8;
    }
    int wslot = (tid & ~63);                        // wave-uniform
    u16* lds_a[4]; u16* lds_b[4];
    #pragma unroll
    for (int pp = 0; pp < 4; pp++) {
        lds_a[pp] = As + (size_t)(pp * 256 + wslot) * 8;
        lds_b[pp] = Bs + (size_t)(pp * 256 + wslot) * 8;
    }

    int lrow = lane & 15;
    int kq   = lane >> 4;
    int mloc[4], nloc[4];
    #pragma unroll
    for (int i = 0; i < 4; i++) {
        mloc[i] = wr * 64 + i * 16 + lrow;
        nloc[i] = wc * 64 + i * 16 + lrow;
    }

    f32x4 acc[4][4] = {};

    for (int kb = 0; kb < HDIM; kb += BK) {
        __syncthreads();
        #pragma unroll
        for (int pp = 0; pp < 4; pp++) {
            __builtin_amdgcn_global_load_lds((gptr_t)(a_src[pp] + kb),
                                             (lptr_t)lds_a[pp], 16, 0, 0);
            __builtin_amdgcn_global_load_lds((gptr_t)(b_src[pp] + kb),
                                             (lptr_t)lds_b[pp], 16, 0, 0);
        }
        __syncthreads();

        #pragma unroll
        for (int s = 0; s < 2; s++) {
            int chunk = s * 4 + kq;
            bf16x8 a[4], b[4];
            #pragma unroll
            for (int i = 0; i < 4; i++) {
                int aslot = (mloc[i] << 3) | (chunk ^ (mloc[i] & 7));
                int bslot = (nloc[i] << 3) | (chunk ^ (nloc[i] & 7));
                a[i] = *(const bf16x8*)(As + aslot * 8);
                b[i] = *(const bf16x8*)(Bs + bslot * 8);
            }
            #pragma unroll
            for (int mt = 0; mt < 4; mt++)
                #pragma unroll
                for (int nt = 0; nt < 4; nt++)
                    acc[mt][nt] = __builtin_amdgcn_mfma_f32_16x16x32_bf16(
                                      a[mt], b[nt], acc[mt][nt], 0, 0, 0);
        }
    }

    int srow = (lane >> 4) * 4;
    #pragma unroll
    for (int mt = 0; mt < 4; mt++) {
        #pragma unroll
        for (int r = 0; r < 4; r++) {
            int row = rowBase + wr * 64 + mt * 16 + srow + r;
            if (row < count) {
                int   tok = rlist[row];
                float wgt = wlist[row];
                #pragma unroll
                for (int nt = 0; nt < 4; nt++) {
                    int col = nb + wc * 64 + nt * 16 + lrow;
                    atomicAdd(out + (size_t)tok * HDIM + col, wgt * acc[mt][nt][r]);
                }
            }
        }
    }
}

extern "C" void kernel_launch(void* const* d_in, const int* in_sizes, int n_in,
                              void* d_out, int out_size, void* d_ws, size_t ws_size,
                              hipStream_t stream) {
    const float* x  = (const float*)d_in[0];   // [T, H]
    const float* gw = (const float*)d_in[1];   // [E, H]
    const float* ew = (const float*)d_in[2];   // [E, H, H]
    float* out    = (float*)d_out;             // [T, H] fp32
    float* logits = out + (size_t)T_TOK * HDIM;

    char* ws = (char*)d_ws;
    int*   cnt  = (int*)ws;                                   // 32 B
    int*   rows = (int*)(ws + 1024);                          // 256 KB
    float* wts  = (float*)(ws + 1024 + 262144);               // 256 KB
    u16*   xb   = (u16*)(ws + 1024 + 2 * 262144);             // 32 MB
    u16*   wb   = xb + (size_t)T_TOK * HDIM;                  // 64 MB

    hipMemsetAsync(d_out, 0, (size_t)T_TOK * HDIM * sizeof(float), stream);
    hipMemsetAsync(cnt, 0, NEXP * sizeof(int), stream);

    int nw8 = NEXP * HDIM * HDIM / 8;
    cvt_kernel<<<(nw8 + 255) / 256, 256, 0, stream>>>(ew, wb, nw8);

    router_kernel<<<T_TOK / RTOK, 256, 0, stream>>>(x, gw, xb, logits, cnt, rows, wts);

    moe_gemm<<<NEXP * 64 * 16, 256, 0, stream>>>(xb, wb, cnt, rows, wts, out);
}